// Round 4
// baseline (138.500 us; speedup 1.0000x reference)
//
#include <hip/hip_runtime.h>

// PointCrop2D: out[b,i,j,c] = in-bounds ? images[b, y-112+i, x-112+j, c] : -2.0f
// B=32, H=W=512, C=3, CROP=224, fill = (0-0.45)/0.225 = -2.0
// Fast path: source misalignment off = (3*colbase)&3 is wave-uniform (waves never
// straddle batches: 150528 floats/image % 256 floats/wave == 0), so interior
// threads use 1-2 ALIGNED dwordx4 loads + uniform register select instead of
// 4 scalar loads.

#define B_N   32
#define H_N   512
#define W_N   512
#define C_N   3
#define CROP  224
#define DIA   112
#define FILLV (-2.0f)

typedef float vf4 __attribute__((ext_vector_type(4)));  // native vector: works with __builtin_nontemporal_store

__global__ __launch_bounds__(256)
void PointCrop2D_27943057227941_kernel(const float* __restrict__ points,
                                       const float* __restrict__ images,
                                       float* __restrict__ out)
{
    const int ROWF   = CROP * C_N;          // 672 floats per output row
    const int IMGF   = CROP * ROWF;         // 150528 floats per output image
    const int TOTALV = (B_N * IMGF) / 4;    // 1204224 float4 stores

    int g = blockIdx.x * blockDim.x + threadIdx.x;
    if (g >= TOTALV) return;

    int pflat = g * 4;
    int b   = pflat / IMGF;
    int rem = pflat - b * IMGF;
    int i   = rem / ROWF;
    int p   = rem - i * ROWF;               // [0,672), multiple of 4

    // points layout (B,3,3): x = points[b,0,0] ; y = points[b,1,0]
    int xp = (int)points[b * 9 + 0];
    int yp = (int)points[b * 9 + 3];
    int x  = min(max(xp, 1), W_N - 2);
    int y  = min(max(yp, 1), H_N - 2);

    int  r     = y - DIA + i;                 // source image row
    bool rowok = (r >= 0) && (r <= H_N - 2);  // row 511 is always fill
    int  ra    = min(max(r, 0), H_N - 1);
    int  colbase = x - DIA;

    const float* rowptr = images + ((size_t)b * H_N + (size_t)ra) * (W_N * C_N);

    int j0  = p / 3;
    int c0  = p - j0 * 3;
    int cc0 = colbase + j0;                  // column of first element
    int cc3 = colbase + (p + 3) / 3;         // column of last element

    // wave-uniform misalignment of the source float4 (p % 4 == 0)
    int off = __builtin_amdgcn_readfirstlane((colbase * 3) & 3);

    vf4 v;
    bool fast = rowok && (cc0 >= 1) && (cc3 <= W_N - 2);
    if (fast) {
        // aligned window [A, A+8) covers the 4 needed floats; stays in-buffer:
        // A >= rowptr (cc0>=1), A+7 < end of images for all (b, r<=510).
        const float* A  = rowptr + (colbase * 3 + p - off);
        const vf4*   A4 = reinterpret_cast<const vf4*>(A);
        if (off == 0) {
            v = A4[0];
        } else {
            vf4 v0 = A4[0];
            vf4 v1 = A4[1];
            if (off == 1)      v = (vf4){v0.y, v0.z, v0.w, v1.x};
            else if (off == 2) v = (vf4){v0.z, v0.w, v1.x, v1.y};
            else               v = (vf4){v0.w, v1.x, v1.y, v1.z};
        }
    } else {
        // slow path: per-element clamped + predicated scalar loads
        int j = j0, c = c0;
        float tmp[4];
#pragma unroll
        for (int k = 0; k < 4; ++k) {
            int  cc  = colbase + j;
            bool ok  = rowok && (cc >= 0) && (cc <= W_N - 2);
            int  cca = min(max(cc, 0), W_N - 1);
            tmp[k] = ok ? rowptr[cca * 3 + c] : FILLV;
            ++c;
            if (c == 3) { c = 0; ++j; }
        }
        v = (vf4){tmp[0], tmp[1], tmp[2], tmp[3]};
    }

    __builtin_nontemporal_store(v, reinterpret_cast<vf4*>(out) + g);
}

extern "C" void kernel_launch(void* const* d_in, const int* in_sizes, int n_in,
                              void* d_out, int out_size, void* d_ws, size_t ws_size,
                              hipStream_t stream) {
    const float* points = (const float*)d_in[0];
    const float* images = (const float*)d_in[1];
    float* out = (float*)d_out;

    const int TOTALV = (B_N * CROP * CROP * C_N) / 4;   // 1204224
    const int block = 256;
    const int grid  = (TOTALV + block - 1) / block;     // 4704

    PointCrop2D_27943057227941_kernel<<<grid, block, 0, stream>>>(points, images, out);
}

// Round 5
// 136.171 us; speedup vs baseline: 1.0171x; 1.0171x over previous
//
#include <hip/hip_runtime.h>

// PointCrop2D: out[b,i,j,c] = in-bounds ? images[b, y-112+i, x-112+j, c] : -2.0f
// B=32, H=W=512, C=3, CROP=224, fill = (0-0.45)/0.225 = -2.0
//
// Structure: each WAVE owns a 1024-float output tile (1024 | 150528, so batch b,
// colbase, and source misalignment off are wave-uniform). Each thread handles 4
// float4 chunks spaced 256 floats apart -> every load/store instruction covers a
// contiguous 1KB wave segment (perfectly coalesced), and all 4 loads issue before
// any store (4x MLP per wave). Per-thread setup (b-divide, point loads, clamps)
// amortized over 16 output floats.

#define B_N   32
#define H_N   512
#define W_N   512
#define C_N   3
#define CROP  224
#define DIA   112
#define FILLV (-2.0f)

typedef float vf4 __attribute__((ext_vector_type(4)));

__global__ __launch_bounds__(256)
void PointCrop2D_27943057227941_kernel(const float* __restrict__ points,
                                       const float* __restrict__ images,
                                       float* __restrict__ out)
{
    const int ROWF = CROP * C_N;            // 672 floats per output row
    const int IMGF = CROP * ROWF;           // 150528 floats per output image

    // wave tile = 1024 floats; block tile = 4096 floats; total 4,816,896 floats
    int lane = threadIdx.x & 63;
    int wid  = threadIdx.x >> 6;
    int pflat0 = blockIdx.x * 4096 + wid * 1024 + lane * 4;   // k-th chunk: +k*256

    // b is wave-uniform (1024 | 150528)
    int b    = pflat0 / IMGF;
    int rem0 = pflat0 - b * IMGF;

    // points layout (B,3,3): x = points[b,0,0] ; y = points[b,1,0]
    int xp = (int)points[b * 9 + 0];
    int yp = (int)points[b * 9 + 3];
    int x  = min(max(xp, 1), W_N - 2);
    int y  = min(max(yp, 1), H_N - 2);
    int colbase = x - DIA;

    const float* imgbase = images + (size_t)b * (H_N * (size_t)(W_N * C_N));

    // wave-uniform misalignment of any source float4 (p % 4 == 0 always)
    int off = __builtin_amdgcn_readfirstlane((colbase * 3) & 3);

    vf4 v[4];
#pragma unroll
    for (int k = 0; k < 4; ++k) {
        int rem = rem0 + k * 256;
        int i   = rem / ROWF;
        int p   = rem - i * ROWF;            // [0,672), multiple of 4

        int  r     = y - DIA + i;
        bool rowok = (r >= 0) && (r <= H_N - 2);   // row 511 is always fill
        int  ra    = min(max(r, 0), H_N - 1);
        const float* rowptr = imgbase + (size_t)ra * (W_N * C_N);

        int j0  = p / 3;
        int cc0 = colbase + j0;                    // column of first element
        int cc3 = colbase + (p + 3) / 3;           // column of last element

        bool fast = rowok && (cc0 >= 1) && (cc3 <= W_N - 2);
        if (fast) {
            // aligned window [A, A+8) covers the 4 needed floats; in-buffer:
            // A >= rowptr, and A+8 <= rowptr + 1536 (stays inside the row).
            const float* A  = rowptr + (colbase * 3 + p - off);
            const vf4*   A4 = reinterpret_cast<const vf4*>(A);
            if (off == 0) {
                v[k] = A4[0];
            } else {
                vf4 v0 = A4[0];
                vf4 v1 = A4[1];
                if (off == 1)      v[k] = (vf4){v0.y, v0.z, v0.w, v1.x};
                else if (off == 2) v[k] = (vf4){v0.z, v0.w, v1.x, v1.y};
                else               v[k] = (vf4){v0.w, v1.x, v1.y, v1.z};
            }
        } else {
            int j = j0, c = p - j0 * 3;
            float tmp[4];
#pragma unroll
            for (int e = 0; e < 4; ++e) {
                int  cc  = colbase + j;
                bool ok  = rowok && (cc >= 0) && (cc <= W_N - 2);
                int  cca = min(max(cc, 0), W_N - 1);
                tmp[e] = ok ? rowptr[cca * 3 + c] : FILLV;
                ++c;
                if (c == 3) { c = 0; ++j; }
            }
            v[k] = (vf4){tmp[0], tmp[1], tmp[2], tmp[3]};
        }
    }

    vf4* outv = reinterpret_cast<vf4*>(out) + (pflat0 >> 2);
#pragma unroll
    for (int k = 0; k < 4; ++k)
        __builtin_nontemporal_store(v[k], outv + k * 64);
}

extern "C" void kernel_launch(void* const* d_in, const int* in_sizes, int n_in,
                              void* d_out, int out_size, void* d_ws, size_t ws_size,
                              hipStream_t stream) {
    const float* points = (const float*)d_in[0];
    const float* images = (const float*)d_in[1];
    float* out = (float*)d_out;

    // 4,816,896 floats total / 4096 floats per block = 1176 blocks
    const int grid = (B_N * CROP * CROP * C_N) / 4096;

    PointCrop2D_27943057227941_kernel<<<grid, 256, 0, stream>>>(points, images, out);
}